// Round 11
// baseline (129.840 us; speedup 1.0000x reference)
//
#include <hip/hip_runtime.h>
#include <hip/hip_bf16.h>

// R23: == R22 (512 thr, 2 waves/SIMD, 2-barrier transposed-logit; dur
// 101.19, best) with WINDOW REMOVAL ==
// R22 post-mortem: TLP confirmed (-4.9us). Refined model: each phase ~= one
// latency window (issue independent loads, wait once); kernel = ~14 windows
// + 2 barriers + entry. Lever now = fewer/cheaper windows, not more width.
// Changes:
//  1. WCOMP FUSION: w_eff = sum_n att[n] * wcomp[r][n], where wcomp[225][100]
//     = composite(vals[n], cw) is INPUT-ONLY -> computed distributed at
//     entry (176 entries/block, ~20 MACs each, global reads) into ws;
//     bar1 publishes. C' runs kern1 (t<225) PARALLEL w_eff (t 256..480)
//     in one phase -> one window removed from the longest chain.
//     Algebraically identical (float reassociation only).
//  2. TRANSPOSED PLOG [logit][block]: reduce reads 32 CONTIGUOUS words
//     (2 lines vs 32 scattered lines) -> MALL service collapses. Writer
//     becomes scattered single stores (fire-and-forget, harmless).
//  3. wcomp layout [r][n]: w_eff thread reads 100 contiguous words (7 lines).
// Pre-committed: dur <=99.5 -> keep merging windows. ~101 flat -> remaining
// is entry+straggler floor; near done.
// Ledger (measured): agent acquire/release fences forbidden (R4); cross-block
// data sc1 relaxed-agent only (R8); no dynamic-indexed register arrays (R7);
// no rolled global-load loops (R11); entry prefetch of static loads (R12);
// NO long-lived prefetch regs across barriers - stage via LDS (R14/R15);
// dur_us is ground truth, rocprof inflates poll loops ~5x, barrier ~1.4us
// (R16/R19); distributed barrier neutral (R18); warm-dup 22us (R19); work
// redistribution -3.6us (R20); code size -1.5us (R21); 512thr TLP -4.9us
// (R22). Deadlock safety: 128 blocks x 512 thr, launch_bounds(512,1),
// ~22KB LDS, VGPR ~80 -> co-resident on 256 CUs. Barrier state (2x1KB)
// zeroed each call. ws usage: 8KB barriers + plog1/plog2 (2x64KB) + wcomp
// (90KB) ~= 229KB.

#define GRID 128

#define LD1(p)     __hip_atomic_load((p), __ATOMIC_RELAXED, __HIP_MEMORY_SCOPE_AGENT)
#define ST1(p, v)  __hip_atomic_store((p), (v), __ATOMIC_RELAXED, __HIP_MEMORY_SCOPE_AGENT)

__device__ __forceinline__ float sigmoidf_(float z) {
    return 1.0f / (1.0f + expf(-z));
}

// base: 256 words (1KB). arrival[0..127]; release flag at word 160.
// No atomics anywhere: stores + loads only. (R12-validated, R17 form)
__device__ __forceinline__ void gbar(unsigned* base, int blk, int t) {
    asm volatile("s_waitcnt vmcnt(0)" ::: "memory");   // data sc1 stores visible
    __syncthreads();
    if (t == 0) ST1(base + blk, 1u);                   // arrival store, own word
    if (blk == 0) {
        if (t < 128) {                                 // 2 waves poll 128 words
            while (LD1(base + t) == 0u)
                __builtin_amdgcn_s_sleep(8);
        }
        __syncthreads();
        if (t == 0) ST1(base + 160, 1u);               // release flag, own line
    } else {
        if (t == 0) {
            while (LD1(base + 160) == 0u)
                __builtin_amdgcn_s_sleep(8);
        }
        __syncthreads();
    }
    asm volatile("" ::: "memory");
    __syncthreads();
}

// entry tap loads, ONE sample per wave (sample = blk*4 + wrow + rep*512).
__device__ __attribute__((noinline)) float2
key_prefetch(const float* __restrict__ in, int mul, int dbl, int blk,
             int lane, int wrow, int rep) {
    int s = blk * 4 + wrow + rep * 512;
    int ii = s >> 5, jj = s & 31;
    int qy = (ii * mul) >> 5, qx = (jj * mul) >> 5;
    int by = dbl ? 2 * qy : qy - 1;
    int bx = dbl ? 2 * qx : qx - 1;
    float xa, xb = 0.f;
    {
        int l = lane;                    // < 64 < 75: always a valid tap
        int ci = l / 25, rm = l % 25, r = rm / 5, cc = rm % 5;
        int y = by + r, x = bx + cc;
        xa = ((unsigned)y < 1024u && (unsigned)x < 1024u)
             ? 2.0f * in[ci * 1048576 + y * 1024 + x] - 1.0f : 0.f;
    }
    if (lane < 11) {
        int l = lane + 64;
        int ci = l / 25, rm = l % 25, r = rm / 5, cc = rm % 5;
        int y = by + r, x = bx + cc;
        xb = ((unsigned)y < 1024u && (unsigned)x < 1024u)
             ? 2.0f * in[ci * 1048576 + y * 1024 + x] - 1.0f : 0.f;
    }
    return make_float2(xa, xb);
}

// key value from taps -> skv LDS ([c*8 + rep*4 + wrow]); one sample per wave.
__device__ __attribute__((noinline)) void
key_stage(const float* __restrict__ sw, const float* __restrict__ sb,
          float xa, float xb, float* __restrict__ skv,
          int lane, int wrow, int rep) {
    float p0 = xa * sw[lane];
    float p1 = xa * sw[75 + lane];
    float p2 = xa * sw[150 + lane];
    if (lane < 11) {
        p0 += xb * sw[64 + lane];
        p1 += xb * sw[139 + lane];
        p2 += xb * sw[214 + lane];
    }
#pragma unroll
    for (int off = 32; off > 0; off >>= 1) {
        p0 += __shfl_xor(p0, off, 64);
        p1 += __shfl_xor(p1, off, 64);
        p2 += __shfl_xor(p2, off, 64);
    }
    if (lane == 0) {
        skv[0 * 8 + rep * 4 + wrow] = sigmoidf_(p0 + sb[0]);
        skv[1 * 8 + rep * 4 + wrow] = sigmoidf_(p1 + sb[1]);
        skv[2 * 8 + rep * 4 + wrow] = sigmoidf_(p2 + sb[2]);
    }
}

// logit partial (skc x skv) -> plog[logit][block] (TRANSPOSED); one copy.
__device__ __attribute__((noinline)) void
logit_partial(const float* __restrict__ skc, const float* __restrict__ skv,
              float* __restrict__ plog, int blk, int t) {
    if (t < 100) {
        float s = 0.f;
        const float* kc = skc + t * 25;
#pragma unroll
        for (int i = 0; i < 24; ++i) s += kc[i] * skv[i];
        ST1(plog + t * 128 + blk, s);
    }
}

// 4-group split reduce of plog[logit][block] -> pr[4][104]; 32 CONTIGUOUS
// words (2 lines) per thread.
__device__ __attribute__((noinline)) void
reduce_split(const float* __restrict__ plog, float* __restrict__ pr, int t) {
    int g = t >> 7, tq = t & 127;
    if (tq < 100) {
        const float* p = plog + tq * 128 + g * 32;
        float s0 = 0.f, s1 = 0.f, s2 = 0.f, s3 = 0.f;
#pragma unroll
        for (int b = 0; b < 8; ++b) {
            s0 += LD1(p + 4 * b + 0);
            s1 += LD1(p + 4 * b + 1);
            s2 += LD1(p + 4 * b + 2);
            s3 += LD1(p + 4 * b + 3);
        }
        pr[g * 104 + tq] = (s0 + s1) + (s2 + s3);
    }
}

// softmax over sum of 4 partials, i<100 -> satt; one copy (has syncthreads).
__device__ __attribute__((noinline)) void
softmax_lds(const float* __restrict__ pr, float* __restrict__ satt,
            int lane, int wv) {
    if (wv == 0) {
        float v1 = (pr[lane] + pr[104 + lane]) + (pr[208 + lane] + pr[312 + lane]);
        float v2 = -3.4e38f;
        if (lane + 64 < 100) {
            int q = lane + 64;
            v2 = (pr[q] + pr[104 + q]) + (pr[208 + q] + pr[312 + q]);
        }
        float mx = fmaxf(v1, v2);
#pragma unroll
        for (int off = 32; off > 0; off >>= 1) mx = fmaxf(mx, __shfl_xor(mx, off, 64));
        float e1 = expf(v1 - mx);
        float e2 = (lane + 64 < 100) ? expf(v2 - mx) : 0.f;
        float s = e1 + e2;
#pragma unroll
        for (int off = 32; off > 0; off >>= 1) s += __shfl_xor(s, off, 64);
        float inv = 1.0f / s;
        satt[lane] = e1 * inv;
        if (lane + 64 < 100) satt[lane + 64] = e2 * inv;
    }
    __syncthreads();
}

// kern matvec: dst[t] = sum_n vals[n][t]*satt[n], dual accumulators; one copy.
__device__ __attribute__((noinline)) void
kern_phase(const float* __restrict__ vals, const float* __restrict__ satt,
           float* __restrict__ dst, int t) {
    if (t < 225) {
        float sa = 0.f, sb2 = 0.f;
#pragma unroll
        for (int n = 0; n < 50; ++n) {
            sa  += vals[(2 * n) * 225 + t] * satt[2 * n];
            sb2 += vals[(2 * n + 1) * 225 + t] * satt[2 * n + 1];
        }
        dst[t] = sa + sb2;
    }
}

__global__ __launch_bounds__(512, 1) void k_fused(
    const float* __restrict__ in, const float* __restrict__ cw,
    const float* __restrict__ cb, const float* __restrict__ keys,
    const float* __restrict__ vals, float* __restrict__ out,
    float* __restrict__ ws, unsigned* __restrict__ ctr)
{
    __shared__ float smem[5536];
    float* sk1  = smem;          // 225  kern1 (persists to tables)
    float* sk2  = smem + 232;    // 225  kern2
    float* satt = smem + 464;    // 100  softmax
    float* sw   = smem + 568;    // 225  conv weights, then w_eff
    float* sb   = smem + 800;    // 3    bias
    float* skv  = smem + 808;    // 24   block's key samples
    float* pr   = smem + 832;    // 416  reduce partials [4][104]
    float* skc  = smem + 1248;   // 2500 keys cols [t*25 + c*8+r*4+w]
    float* sWk  = smem + 3748;   // 468  W subset [(ci*3+o)*nk13 + k*13 + f]
    float* sWxk = smem + 4216;   // 36   Wx subset [(ci*3+o)*nk + k]
    float* sWy  = smem + 4252;   // 117  (blk 0 only)
    float* sWxy = smem + 4372;   // 9    (blk 0 only)
    float* sga  = smem + 4384;   // 1152 G combine [(h-1)*384 + ch*128 + j]

    float* plog1 = ws;           // [100 logits][128 blocks] (transposed)
    float* plog2 = ws + 16384;
    float* wcomp = ws + 32768;   // [225 r][100 n] input-only composite

    const int t = threadIdx.x, lane = t & 63, wv = t >> 6;
    const int wrow = wv & 3, rep = wv >> 2;
    const int blk = blockIdx.x;

    // ---- entry prefetch: one sample per wave (s2v = 2 regs across bar1) ----
    float2 s1v = key_prefetch(in, 510, 1, blk, lane, wrow, rep);
    float2 s2v = key_prefetch(in, 1022, 0, blk, lane, wrow, rep);

    // ---- entry: keys columns for this block's 8 samples -> LDS (R14 fix) ----
    if (t < 100) {
        const float* kr = keys + t * 3072 + blk * 4;
#pragma unroll
        for (int c = 0; c < 3; ++c)
#pragma unroll
            for (int r = 0; r < 2; ++r) {
                float4 kk = *reinterpret_cast<const float4*>(kr + c * 1024 + r * 512);
                int o = t * 25 + c * 8 + r * 4;
                skc[o]     = kk.x;
                skc[o + 1] = kk.y;
                skc[o + 2] = kk.z;
                skc[o + 3] = kk.w;
            }
    }

    // ---- entry: distributed wcomp[r][n] = composite(vals[n], cw) -> ws ----
    // Input-only; bar1 publishes. 176 entries/block, ~20 MACs each (global).
    if (t < 176) {
        int flat = blk * 176 + t;
        if (flat < 22500) {
            int n = flat / 225, r = flat % 225;
            int co = r / 75, rem = r % 75, ci = rem / 25;
            int a = (rem % 25) / 5, bb = rem % 5;
            float s = 0.f;
#pragma unroll
            for (int c = 0; c < 5; ++c) {
                int u = c + 2 * a - 4;
                if ((unsigned)u >= 5u) continue;
#pragma unroll
                for (int d = 0; d < 5; ++d) {
                    int v = d + 2 * bb - 4;
                    if ((unsigned)v >= 5u) continue;
#pragma unroll
                    for (int cm = 0; cm < 3; ++cm)
                        s += vals[n * 225 + ci * 75 + cm * 25 + c * 5 + d]
                           * cw[co * 75 + cm * 25 + u * 5 + v];
                }
            }
            ST1(wcomp + r * 100 + n, s);
        }
    }

    // ---- G geometry (j = output col, h = l-slot 0..3; taps direct global) ----
    const int j = t & 127, h = t >> 7;
    const int R = (blk * 4093) >> 7;
    const int C = (j * 4093) >> 7;
    const int ybase = (R + 6) >> 2, r0 = (R + 6) & 3, nk = (r0 == 0) ? 4 : 3;
    const int xbase = (C + 6) >> 2, f0 = (C + 6) & 3, nl = (f0 == 0) ? 4 : 3;
    const int nk13 = nk * 13;

    if (t < 225) sw[t] = cw[t];
    if (t < 3)   sb[t] = cb[t];
    __syncthreads();

    // ---- A: key1 samples -> skv, partial logits -> plog1 (all blocks) ----
    key_stage(sw, sb, s1v.x, s1v.y, skv, lane, wrow, rep);
    __syncthreads();
    logit_partial(skc, skv, plog1, blk, t);
    gbar(ctr, blk, t);

    // ---- C' (replicated): reduce -> softmax -> {kern1 PARALLEL w_eff} ----
    reduce_split(plog1, pr, t);
    __syncthreads();
    softmax_lds(pr, satt, lane, wv);
    kern_phase(vals, satt, sk1, t);          // t < 225
    if (t >= 256 && t < 481) {               // w_eff via wcomp, waves 4-7
        int r = t - 256;
        const float* wc = wcomp + r * 100;
        float sa = 0.f, sb2 = 0.f;
#pragma unroll
        for (int n = 0; n < 50; ++n) {
            sa  += LD1(wc + 2 * n)     * satt[2 * n];
            sb2 += LD1(wc + 2 * n + 1) * satt[2 * n + 1];
        }
        sw[r] = sa + sb2;                    // nobody reads old sw here
    }
    __syncthreads();

    // ---- D: key2 samples via w_eff -> skv, partials -> plog2 ----
    key_stage(sw, sb, s2v.x, s2v.y, skv, lane, wrow, rep);
    __syncthreads();
    logit_partial(skc, skv, plog2, blk, t);
    gbar(ctr + 256, blk, t);

    // ---- F' (replicated): reduce -> softmax -> kern2 -> tables ----
    reduce_split(plog2, pr, t);
    __syncthreads();
    softmax_lds(pr, satt, lane, wv);
    kern_phase(vals, satt, sk2, t);
    __syncthreads();
    // W subset: only rows e = r0 + 4k (k < nk) that THIS block's G uses.
    for (int idx = t; idx < 9 * nk13; idx += 512) {
        int cio = idx / nk13, rem = idx % nk13;
        int k = rem / 13, f = rem % 13;
        int e = r0 + 4 * k;
        int ci = cio / 3, o = cio % 3;
        float s = 0.f;
#pragma unroll
        for (int c = 0; c < 5; ++c) {
            int a = e - 2 * c;
            if ((unsigned)a >= 5u) continue;
#pragma unroll
            for (int d = 0; d < 5; ++d) {
                int b2 = f - 2 * d;
                if ((unsigned)b2 >= 5u) continue;
#pragma unroll
                for (int cm = 0; cm < 3; ++cm)
                    s += sk1[ci * 75 + cm * 25 + c * 5 + d] * sk2[cm * 75 + o * 25 + a * 5 + b2];
            }
        }
        sWk[idx] = s;
    }
    if (t >= 472 && t < 472 + 9 * nk) {   // Wx subset (phantom col), idle threads
        int q = t - 472;
        int cio = q / nk, k = q % nk;
        int e = r0 + 4 * k;
        int ci = cio / 3, o = cio % 3;
        float s = 0.f;
#pragma unroll
        for (int c = 0; c < 5; ++c) {
            int a = e - 2 * c;
            if ((unsigned)a >= 5u) continue;
#pragma unroll
            for (int cm = 0; cm < 3; ++cm)
                s += sk1[ci * 75 + cm * 25 + c * 5 + 1] * sk2[cm * 75 + o * 25 + a * 5 + 4];
        }
        sWxk[cio * nk + k] = s;
    }
    if (blk == 0) {   // R==0 only for block 0: Wy full f-range + Wxy
        if (t >= 256 && t < 256 + 117) {
            int q = t - 256;
            int ci = q / 39, o = (q % 39) / 13, f = q % 13;
            float s = 0.f;
#pragma unroll
            for (int d = 0; d < 5; ++d) {
                int b2 = f - 2 * d;
                if ((unsigned)b2 >= 5u) continue;
#pragma unroll
                for (int cm = 0; cm < 3; ++cm)
                    s += sk1[ci * 75 + cm * 25 + 5 + d] * sk2[cm * 75 + o * 25 + 20 + b2];
            }
            sWy[(ci * 3 + o) * 13 + f] = s;
        }
        if (t >= 384 && t < 393) {
            int q = t - 384;
            int ci = q / 3, o = q % 3;
            float s = 0.f;
#pragma unroll
            for (int cm = 0; cm < 3; ++cm)
                s += sk1[ci * 75 + cm * 25 + 5 + 1] * sk2[cm * 75 + o * 25 + 20 + 4];
            sWxy[ci * 3 + o] = s;
        }
    }
    __syncthreads();

    // ---- G: 4-way split (h = l-slot), taps direct global, sga combine ----
    {
        float a0 = 0.f, a1 = 0.f, a2 = 0.f;
        const int l = h;
        if (l < nl) {
            int ix = xbase - l;
            if ((unsigned)ix < 1024u) {
                int f = f0 + 4 * l;
#pragma unroll
                for (int k = 0; k < 4; ++k) {
                    if (k < nk) {
                        int iy = ybase - k;
                        if ((unsigned)iy < 1024u) {
                            int wi = k * 13 + f;
                            int off = iy * 1024 + ix;
                            float x0 = 2.0f * in[off] - 1.0f;
                            float x1 = 2.0f * in[1048576 + off] - 1.0f;
                            float x2 = 2.0f * in[2097152 + off] - 1.0f;
                            a0 += x0 * sWk[wi]            + x1 * sWk[3 * nk13 + wi] + x2 * sWk[6 * nk13 + wi];
                            a1 += x0 * sWk[nk13 + wi]     + x1 * sWk[4 * nk13 + wi] + x2 * sWk[7 * nk13 + wi];
                            a2 += x0 * sWk[2 * nk13 + wi] + x1 * sWk[5 * nk13 + wi] + x2 * sWk[8 * nk13 + wi];
                        }
                    }
                }
                if (R == 0) {   // block 0: phantom-row correction for own l
                    float x0 = 2.0f * in[ix] - 1.0f;
                    float x1 = 2.0f * in[1048576 + ix] - 1.0f;
                    float x2 = 2.0f * in[2097152 + ix] - 1.0f;
                    a0 -= x0 * sWy[f]      + x1 * sWy[39 + f] + x2 * sWy[78 + f];
                    a1 -= x0 * sWy[13 + f] + x1 * sWy[52 + f] + x2 * sWy[91 + f];
                    a2 -= x0 * sWy[26 + f] + x1 * sWy[65 + f] + x2 * sWy[104 + f];
                }
            }
        }
        if (C == 0 && h == 0) {   // j==0: phantom-col correction, once
#pragma unroll
            for (int k = 0; k < 4; ++k) {
                if (k < nk) {
                    int iy = ybase - k;
                    if ((unsigned)iy < 1024u) {
                        int off = iy * 1024;
                        float x0 = 2.0f * in[off] - 1.0f;
                        float x1 = 2.0f * in[1048576 + off] - 1.0f;
                        float x2 = 2.0f * in[2097152 + off] - 1.0f;
                        a0 -= x0 * sWxk[k]          + x1 * sWxk[3 * nk + k] + x2 * sWxk[6 * nk + k];
                        a1 -= x0 * sWxk[nk + k]     + x1 * sWxk[4 * nk + k] + x2 * sWxk[7 * nk + k];
                        a2 -= x0 * sWxk[2 * nk + k] + x1 * sWxk[5 * nk + k] + x2 * sWxk[8 * nk + k];
                    }
                }
            }
        }
        if (R == 0 && C == 0 && h == 0) {
            float x0 = 2.0f * in[0] - 1.0f;
            float x1 = 2.0f * in[1048576] - 1.0f;
            float x2 = 2.0f * in[2097152] - 1.0f;
            a0 += x0 * sWxy[0] + x1 * sWxy[3] + x2 * sWxy[6];
            a1 += x0 * sWxy[1] + x1 * sWxy[4] + x2 * sWxy[7];
            a2 += x0 * sWxy[2] + x1 * sWxy[5] + x2 * sWxy[8];
        }
        if (h > 0) {
            int base = (h - 1) * 384;
            sga[base + j] = a0; sga[base + 128 + j] = a1; sga[base + 256 + j] = a2;
        }
        __syncthreads();
        if (h == 0) {
            int T = blk * 128 + j;
            float b0 = a0 + sga[j]       + sga[384 + j]       + sga[768 + j];
            float b1 = a1 + sga[128 + j] + sga[384 + 128 + j] + sga[768 + 128 + j];
            float b2 = a2 + sga[256 + j] + sga[384 + 256 + j] + sga[768 + 256 + j];
            out[T]             = sigmoidf_(b0);
            out[16384 + T]     = sigmoidf_(b1);
            out[2 * 16384 + T] = sigmoidf_(b2);
        }
    }
}

extern "C" void kernel_launch(void* const* d_in, const int* in_sizes, int n_in,
                              void* d_out, int out_size, void* d_ws, size_t ws_size,
                              hipStream_t stream) {
    const float* in   = (const float*)d_in[0];   // [3,1024,1024]
    const float* cw   = (const float*)d_in[1];   // [3,3,5,5]
    const float* cb   = (const float*)d_in[2];   // [3]
    const float* keys = (const float*)d_in[3];   // [100,3072]
    const float* vals = (const float*)d_in[4];   // [100,225]
    float* out = (float*)d_out;                  // [3,128,128] fp32

    unsigned* ctr = (unsigned*)d_ws;             // 2 barriers x 1KB (store-based)
    float* wsf = (float*)((char*)d_ws + 8192);   // plog1/plog2/wcomp scratch

    hipMemsetAsync(d_ws, 0, 2048, stream);       // zero barrier state
    k_fused<<<GRID, 512, 0, stream>>>(in, cw, cb, keys, vals, out, wsf, ctr);
}

// Round 12
// 102.304 us; speedup vs baseline: 1.2692x; 1.2692x over previous
//
#include <hip/hip_runtime.h>
#include <hip/hip_bf16.h>

// R24: == R22 EXACTLY (512 thr, 2 waves/SIMD, 2-barrier, plog[block][logit];
// dur 101.19 best) + wcomp w_eff-fusion with CORRECTED COALESCED LAYOUT ==
// R23 post-mortem (-28.7us regression, mechanism identified): I transposed
// plog and laid out wcomp for PER-THREAD contiguity, which destroys
// PER-INSTRUCTION cross-lane coalescing. R22's plog[block][logit] was
// already optimal: reduce instruction b has lanes reading consecutive
// addresses (1 line/instr); my transpose made every instruction touch 64
// lines at stride 512B (WRITE_SIZE 304->1703KB = partial-line-store
// amplification). LEDGER: coalescing = cross-lane per instruction;
// per-thread contiguity is the anti-pattern.
// This round keeps ONLY the (sound) window-removal idea, layout-corrected:
//   wcomp[flat = n*225 + r] = composite(vals[n], cw)  [input-only]
//   - entry writer: consecutive t -> consecutive flat -> coalesced stores
//   - C' reader: thread r reads wcomp[n*225+r]; lanes r consecutive ->
//     coalesced (~1 line/instr), 100 independent loads, ONE MALL window,
//     on waves 4-7 IN PARALLEL with kern1 (waves 0-3) -> w_eff phase+sync
//     removed from the critical chain. Algebraically identical.
// Pre-committed: dur 99-101 -> fusion pays, keep. >=101.5 -> wash; revert
// to pure R22, declare serial-chain floor.
// Ledger (measured): agent acquire/release fences forbidden (R4); cross-block
// data sc1 relaxed-agent only (R8); no dynamic-indexed register arrays (R7);
// no rolled global-load loops (R11); entry prefetch of static loads (R12);
// NO long-lived prefetch regs across barriers - stage via LDS (R14/R15);
// dur_us is ground truth, rocprof inflates poll loops ~5x, barrier ~1.4us
// (R16/R19); distributed barrier neutral (R18); warm-dup 22us (R19); work
// redistribution -3.6us (R20); code size -1.5us (R21); 512thr TLP -4.9us
// (R22); per-thread-contiguity layouts -28.7us (R23). Deadlock safety:
// 128 blocks x 512 thr, launch_bounds(512,1), ~22KB LDS -> co-resident.
// Barrier state (2x1KB) zeroed each call. ws: 8KB barriers + 2x64KB plog +
// 90KB wcomp.

#define GRID 128

#define LD1(p)     __hip_atomic_load((p), __ATOMIC_RELAXED, __HIP_MEMORY_SCOPE_AGENT)
#define ST1(p, v)  __hip_atomic_store((p), (v), __ATOMIC_RELAXED, __HIP_MEMORY_SCOPE_AGENT)

__device__ __forceinline__ float sigmoidf_(float z) {
    return 1.0f / (1.0f + expf(-z));
}

// base: 256 words (1KB). arrival[0..127]; release flag at word 160.
// No atomics anywhere: stores + loads only. (R12-validated, R17 form)
__device__ __forceinline__ void gbar(unsigned* base, int blk, int t) {
    asm volatile("s_waitcnt vmcnt(0)" ::: "memory");   // data sc1 stores visible
    __syncthreads();
    if (t == 0) ST1(base + blk, 1u);                   // arrival store, own word
    if (blk == 0) {
        if (t < 128) {                                 // 2 waves poll 128 words
            while (LD1(base + t) == 0u)
                __builtin_amdgcn_s_sleep(8);
        }
        __syncthreads();
        if (t == 0) ST1(base + 160, 1u);               // release flag, own line
    } else {
        if (t == 0) {
            while (LD1(base + 160) == 0u)
                __builtin_amdgcn_s_sleep(8);
        }
        __syncthreads();
    }
    asm volatile("" ::: "memory");
    __syncthreads();
}

// entry tap loads, ONE sample per wave (sample = blk*4 + wrow + rep*512).
__device__ __attribute__((noinline)) float2
key_prefetch(const float* __restrict__ in, int mul, int dbl, int blk,
             int lane, int wrow, int rep) {
    int s = blk * 4 + wrow + rep * 512;
    int ii = s >> 5, jj = s & 31;
    int qy = (ii * mul) >> 5, qx = (jj * mul) >> 5;
    int by = dbl ? 2 * qy : qy - 1;
    int bx = dbl ? 2 * qx : qx - 1;
    float xa, xb = 0.f;
    {
        int l = lane;                    // < 64 < 75: always a valid tap
        int ci = l / 25, rm = l % 25, r = rm / 5, cc = rm % 5;
        int y = by + r, x = bx + cc;
        xa = ((unsigned)y < 1024u && (unsigned)x < 1024u)
             ? 2.0f * in[ci * 1048576 + y * 1024 + x] - 1.0f : 0.f;
    }
    if (lane < 11) {
        int l = lane + 64;
        int ci = l / 25, rm = l % 25, r = rm / 5, cc = rm % 5;
        int y = by + r, x = bx + cc;
        xb = ((unsigned)y < 1024u && (unsigned)x < 1024u)
             ? 2.0f * in[ci * 1048576 + y * 1024 + x] - 1.0f : 0.f;
    }
    return make_float2(xa, xb);
}

// key value from taps -> skv LDS ([c*8 + rep*4 + wrow]); one sample per wave.
__device__ __attribute__((noinline)) void
key_stage(const float* __restrict__ sw, const float* __restrict__ sb,
          float xa, float xb, float* __restrict__ skv,
          int lane, int wrow, int rep) {
    float p0 = xa * sw[lane];
    float p1 = xa * sw[75 + lane];
    float p2 = xa * sw[150 + lane];
    if (lane < 11) {
        p0 += xb * sw[64 + lane];
        p1 += xb * sw[139 + lane];
        p2 += xb * sw[214 + lane];
    }
#pragma unroll
    for (int off = 32; off > 0; off >>= 1) {
        p0 += __shfl_xor(p0, off, 64);
        p1 += __shfl_xor(p1, off, 64);
        p2 += __shfl_xor(p2, off, 64);
    }
    if (lane == 0) {
        skv[0 * 8 + rep * 4 + wrow] = sigmoidf_(p0 + sb[0]);
        skv[1 * 8 + rep * 4 + wrow] = sigmoidf_(p1 + sb[1]);
        skv[2 * 8 + rep * 4 + wrow] = sigmoidf_(p2 + sb[2]);
    }
}

// logit partial (skc x skv) -> plog[block][logit] (R22 layout: lane-coalesced
// writes AND lane-coalesced reduce reads); one copy.
__device__ __attribute__((noinline)) void
logit_partial(const float* __restrict__ skc, const float* __restrict__ skv,
              float* __restrict__ plog, int blk, int t) {
    if (t < 100) {
        float s = 0.f;
        const float* kc = skc + t * 25;
#pragma unroll
        for (int i = 0; i < 24; ++i) s += kc[i] * skv[i];
        ST1(plog + blk * 128 + t, s);
    }
}

// 4-group split reduce of plog[block][logit] -> pr[4][104]; per-instruction
// lane-coalesced (lanes tq read consecutive words); 32 loads/thread.
__device__ __attribute__((noinline)) void
reduce_split(const float* __restrict__ plog, float* __restrict__ pr, int t) {
    int g = t >> 7, tq = t & 127;
    if (tq < 100) {
        const float* p = plog + tq + g * 32 * 128;
        float s0 = 0.f, s1 = 0.f, s2 = 0.f, s3 = 0.f;
#pragma unroll
        for (int b = 0; b < 8; ++b) {
            s0 += LD1(p + (4 * b + 0) * 128);
            s1 += LD1(p + (4 * b + 1) * 128);
            s2 += LD1(p + (4 * b + 2) * 128);
            s3 += LD1(p + (4 * b + 3) * 128);
        }
        pr[g * 104 + tq] = (s0 + s1) + (s2 + s3);
    }
}

// softmax over sum of 4 partials, i<100 -> satt; one copy (has syncthreads).
__device__ __attribute__((noinline)) void
softmax_lds(const float* __restrict__ pr, float* __restrict__ satt,
            int lane, int wv) {
    if (wv == 0) {
        float v1 = (pr[lane] + pr[104 + lane]) + (pr[208 + lane] + pr[312 + lane]);
        float v2 = -3.4e38f;
        if (lane + 64 < 100) {
            int q = lane + 64;
            v2 = (pr[q] + pr[104 + q]) + (pr[208 + q] + pr[312 + q]);
        }
        float mx = fmaxf(v1, v2);
#pragma unroll
        for (int off = 32; off > 0; off >>= 1) mx = fmaxf(mx, __shfl_xor(mx, off, 64));
        float e1 = expf(v1 - mx);
        float e2 = (lane + 64 < 100) ? expf(v2 - mx) : 0.f;
        float s = e1 + e2;
#pragma unroll
        for (int off = 32; off > 0; off >>= 1) s += __shfl_xor(s, off, 64);
        float inv = 1.0f / s;
        satt[lane] = e1 * inv;
        if (lane + 64 < 100) satt[lane + 64] = e2 * inv;
    }
    __syncthreads();
}

// kern matvec: dst[t] = sum_n vals[n][t]*satt[n], dual accumulators; one copy.
__device__ __attribute__((noinline)) void
kern_phase(const float* __restrict__ vals, const float* __restrict__ satt,
           float* __restrict__ dst, int t) {
    if (t < 225) {
        float sa = 0.f, sb2 = 0.f;
#pragma unroll
        for (int n = 0; n < 50; ++n) {
            sa  += vals[(2 * n) * 225 + t] * satt[2 * n];
            sb2 += vals[(2 * n + 1) * 225 + t] * satt[2 * n + 1];
        }
        dst[t] = sa + sb2;
    }
}

__global__ __launch_bounds__(512, 1) void k_fused(
    const float* __restrict__ in, const float* __restrict__ cw,
    const float* __restrict__ cb, const float* __restrict__ keys,
    const float* __restrict__ vals, float* __restrict__ out,
    float* __restrict__ ws, unsigned* __restrict__ ctr)
{
    __shared__ float smem[5536];
    float* sk1  = smem;          // 225  kern1 (persists to tables)
    float* sk2  = smem + 232;    // 225  kern2
    float* satt = smem + 464;    // 100  softmax
    float* sw   = smem + 568;    // 225  conv weights, then w_eff
    float* sb   = smem + 800;    // 3    bias
    float* skv  = smem + 808;    // 24   block's key samples
    float* pr   = smem + 832;    // 416  reduce partials [4][104]
    float* skc  = smem + 1248;   // 2500 keys cols [t*25 + c*8+r*4+w]
    float* sWk  = smem + 3748;   // 468  W subset [(ci*3+o)*nk13 + k*13 + f]
    float* sWxk = smem + 4216;   // 36   Wx subset [(ci*3+o)*nk + k]
    float* sWy  = smem + 4252;   // 117  (blk 0 only)
    float* sWxy = smem + 4372;   // 9    (blk 0 only)
    float* sga  = smem + 4384;   // 1152 G combine [(h-1)*384 + ch*128 + j]

    float* plog1 = ws;           // [128 blocks][128 stride], 100 used (R22)
    float* plog2 = ws + 16384;
    float* wcomp = ws + 32768;   // [22500] flat = n*225 + r (coalesced)

    const int t = threadIdx.x, lane = t & 63, wv = t >> 6;
    const int wrow = wv & 3, rep = wv >> 2;
    const int blk = blockIdx.x;

    // ---- entry prefetch: one sample per wave (s2v = 2 regs across bar1) ----
    float2 s1v = key_prefetch(in, 510, 1, blk, lane, wrow, rep);
    float2 s2v = key_prefetch(in, 1022, 0, blk, lane, wrow, rep);

    // ---- entry: keys columns for this block's 8 samples -> LDS (R14 fix) ----
    if (t < 100) {
        const float* kr = keys + t * 3072 + blk * 4;
#pragma unroll
        for (int c = 0; c < 3; ++c)
#pragma unroll
            for (int r = 0; r < 2; ++r) {
                float4 kk = *reinterpret_cast<const float4*>(kr + c * 1024 + r * 512);
                int o = t * 25 + c * 8 + r * 4;
                skc[o]     = kk.x;
                skc[o + 1] = kk.y;
                skc[o + 2] = kk.z;
                skc[o + 3] = kk.w;
            }
    }

    // ---- entry: distributed wcomp[n*225+r] = composite(vals[n], cw) ----
    // Input-only; bar1 publishes. Writes coalesced (consecutive t -> flat).
    if (t < 176) {
        int flat = blk * 176 + t;
        if (flat < 22500) {
            int n = flat / 225, r = flat % 225;
            int co = r / 75, rem = r % 75, ci = rem / 25;
            int a = (rem % 25) / 5, bb = rem % 5;
            float s = 0.f;
#pragma unroll
            for (int c = 0; c < 5; ++c) {
                int u = c + 2 * a - 4;
                if ((unsigned)u >= 5u) continue;
#pragma unroll
                for (int d = 0; d < 5; ++d) {
                    int v = d + 2 * bb - 4;
                    if ((unsigned)v >= 5u) continue;
#pragma unroll
                    for (int cm = 0; cm < 3; ++cm)
                        s += vals[n * 225 + ci * 75 + cm * 25 + c * 5 + d]
                           * cw[co * 75 + cm * 25 + u * 5 + v];
                }
            }
            ST1(wcomp + flat, s);
        }
    }

    // ---- G geometry (j = output col, h = l-slot 0..3; taps direct global) ----
    const int j = t & 127, h = t >> 7;
    const int R = (blk * 4093) >> 7;
    const int C = (j * 4093) >> 7;
    const int ybase = (R + 6) >> 2, r0 = (R + 6) & 3, nk = (r0 == 0) ? 4 : 3;
    const int xbase = (C + 6) >> 2, f0 = (C + 6) & 3, nl = (f0 == 0) ? 4 : 3;
    const int nk13 = nk * 13;

    if (t < 225) sw[t] = cw[t];
    if (t < 3)   sb[t] = cb[t];
    __syncthreads();

    // ---- A: key1 samples -> skv, partial logits -> plog1 (all blocks) ----
    key_stage(sw, sb, s1v.x, s1v.y, skv, lane, wrow, rep);
    __syncthreads();
    logit_partial(skc, skv, plog1, blk, t);
    gbar(ctr, blk, t);

    // ---- C' (replicated): reduce -> softmax -> {kern1 PARALLEL w_eff} ----
    reduce_split(plog1, pr, t);
    __syncthreads();
    softmax_lds(pr, satt, lane, wv);
    kern_phase(vals, satt, sk1, t);          // t < 225 (waves 0-3)
    if (t >= 256 && t < 481) {               // w_eff via wcomp, waves 4-7
        int r = t - 256;
        float sa = 0.f, sb2 = 0.f;
#pragma unroll
        for (int n = 0; n < 50; ++n) {       // lanes r consecutive: coalesced
            sa  += LD1(wcomp + (2 * n) * 225 + r)     * satt[2 * n];
            sb2 += LD1(wcomp + (2 * n + 1) * 225 + r) * satt[2 * n + 1];
        }
        sw[r] = sa + sb2;                    // nobody reads old sw here
    }
    __syncthreads();

    // ---- D: key2 samples via w_eff -> skv, partials -> plog2 ----
    key_stage(sw, sb, s2v.x, s2v.y, skv, lane, wrow, rep);
    __syncthreads();
    logit_partial(skc, skv, plog2, blk, t);
    gbar(ctr + 256, blk, t);

    // ---- F' (replicated): reduce -> softmax -> kern2 -> tables ----
    reduce_split(plog2, pr, t);
    __syncthreads();
    softmax_lds(pr, satt, lane, wv);
    kern_phase(vals, satt, sk2, t);
    __syncthreads();
    // W subset: only rows e = r0 + 4k (k < nk) that THIS block's G uses.
    for (int idx = t; idx < 9 * nk13; idx += 512) {
        int cio = idx / nk13, rem = idx % nk13;
        int k = rem / 13, f = rem % 13;
        int e = r0 + 4 * k;
        int ci = cio / 3, o = cio % 3;
        float s = 0.f;
#pragma unroll
        for (int c = 0; c < 5; ++c) {
            int a = e - 2 * c;
            if ((unsigned)a >= 5u) continue;
#pragma unroll
            for (int d = 0; d < 5; ++d) {
                int b2 = f - 2 * d;
                if ((unsigned)b2 >= 5u) continue;
#pragma unroll
                for (int cm = 0; cm < 3; ++cm)
                    s += sk1[ci * 75 + cm * 25 + c * 5 + d] * sk2[cm * 75 + o * 25 + a * 5 + b2];
            }
        }
        sWk[idx] = s;
    }
    if (t >= 472 && t < 472 + 9 * nk) {   // Wx subset (phantom col), idle threads
        int q = t - 472;
        int cio = q / nk, k = q % nk;
        int e = r0 + 4 * k;
        int ci = cio / 3, o = cio % 3;
        float s = 0.f;
#pragma unroll
        for (int c = 0; c < 5; ++c) {
            int a = e - 2 * c;
            if ((unsigned)a >= 5u) continue;
#pragma unroll
            for (int cm = 0; cm < 3; ++cm)
                s += sk1[ci * 75 + cm * 25 + c * 5 + 1] * sk2[cm * 75 + o * 25 + a * 5 + 4];
        }
        sWxk[cio * nk + k] = s;
    }
    if (blk == 0) {   // R==0 only for block 0: Wy full f-range + Wxy
        if (t >= 256 && t < 256 + 117) {
            int q = t - 256;
            int ci = q / 39, o = (q % 39) / 13, f = q % 13;
            float s = 0.f;
#pragma unroll
            for (int d = 0; d < 5; ++d) {
                int b2 = f - 2 * d;
                if ((unsigned)b2 >= 5u) continue;
#pragma unroll
                for (int cm = 0; cm < 3; ++cm)
                    s += sk1[ci * 75 + cm * 25 + 5 + d] * sk2[cm * 75 + o * 25 + 20 + b2];
            }
            sWy[(ci * 3 + o) * 13 + f] = s;
        }
        if (t >= 384 && t < 393) {
            int q = t - 384;
            int ci = q / 3, o = q % 3;
            float s = 0.f;
#pragma unroll
            for (int cm = 0; cm < 3; ++cm)
                s += sk1[ci * 75 + cm * 25 + 5 + 1] * sk2[cm * 75 + o * 25 + 20 + 4];
            sWxy[ci * 3 + o] = s;
        }
    }
    __syncthreads();

    // ---- G: 4-way split (h = l-slot), taps direct global, sga combine ----
    {
        float a0 = 0.f, a1 = 0.f, a2 = 0.f;
        const int l = h;
        if (l < nl) {
            int ix = xbase - l;
            if ((unsigned)ix < 1024u) {
                int f = f0 + 4 * l;
#pragma unroll
                for (int k = 0; k < 4; ++k) {
                    if (k < nk) {
                        int iy = ybase - k;
                        if ((unsigned)iy < 1024u) {
                            int wi = k * 13 + f;
                            int off = iy * 1024 + ix;
                            float x0 = 2.0f * in[off] - 1.0f;
                            float x1 = 2.0f * in[1048576 + off] - 1.0f;
                            float x2 = 2.0f * in[2097152 + off] - 1.0f;
                            a0 += x0 * sWk[wi]            + x1 * sWk[3 * nk13 + wi] + x2 * sWk[6 * nk13 + wi];
                            a1 += x0 * sWk[nk13 + wi]     + x1 * sWk[4 * nk13 + wi] + x2 * sWk[7 * nk13 + wi];
                            a2 += x0 * sWk[2 * nk13 + wi] + x1 * sWk[5 * nk13 + wi] + x2 * sWk[8 * nk13 + wi];
                        }
                    }
                }
                if (R == 0) {   // block 0: phantom-row correction for own l
                    float x0 = 2.0f * in[ix] - 1.0f;
                    float x1 = 2.0f * in[1048576 + ix] - 1.0f;
                    float x2 = 2.0f * in[2097152 + ix] - 1.0f;
                    a0 -= x0 * sWy[f]      + x1 * sWy[39 + f] + x2 * sWy[78 + f];
                    a1 -= x0 * sWy[13 + f] + x1 * sWy[52 + f] + x2 * sWy[91 + f];
                    a2 -= x0 * sWy[26 + f] + x1 * sWy[65 + f] + x2 * sWy[104 + f];
                }
            }
        }
        if (C == 0 && h == 0) {   // j==0: phantom-col correction, once
#pragma unroll
            for (int k = 0; k < 4; ++k) {
                if (k < nk) {
                    int iy = ybase - k;
                    if ((unsigned)iy < 1024u) {
                        int off = iy * 1024;
                        float x0 = 2.0f * in[off] - 1.0f;
                        float x1 = 2.0f * in[1048576 + off] - 1.0f;
                        float x2 = 2.0f * in[2097152 + off] - 1.0f;
                        a0 -= x0 * sWxk[k]          + x1 * sWxk[3 * nk + k] + x2 * sWxk[6 * nk + k];
                        a1 -= x0 * sWxk[nk + k]     + x1 * sWxk[4 * nk + k] + x2 * sWxk[7 * nk + k];
                        a2 -= x0 * sWxk[2 * nk + k] + x1 * sWxk[5 * nk + k] + x2 * sWxk[8 * nk + k];
                    }
                }
            }
        }
        if (R == 0 && C == 0 && h == 0) {
            float x0 = 2.0f * in[0] - 1.0f;
            float x1 = 2.0f * in[1048576] - 1.0f;
            float x2 = 2.0f * in[2097152] - 1.0f;
            a0 += x0 * sWxy[0] + x1 * sWxy[3] + x2 * sWxy[6];
            a1 += x0 * sWxy[1] + x1 * sWxy[4] + x2 * sWxy[7];
            a2 += x0 * sWxy[2] + x1 * sWxy[5] + x2 * sWxy[8];
        }
        if (h > 0) {
            int base = (h - 1) * 384;
            sga[base + j] = a0; sga[base + 128 + j] = a1; sga[base + 256 + j] = a2;
        }
        __syncthreads();
        if (h == 0) {
            int T = blk * 128 + j;
            float b0 = a0 + sga[j]       + sga[384 + j]       + sga[768 + j];
            float b1 = a1 + sga[128 + j] + sga[384 + 128 + j] + sga[768 + 128 + j];
            float b2 = a2 + sga[256 + j] + sga[384 + 256 + j] + sga[768 + 256 + j];
            out[T]             = sigmoidf_(b0);
            out[16384 + T]     = sigmoidf_(b1);
            out[2 * 16384 + T] = sigmoidf_(b2);
        }
    }
}

extern "C" void kernel_launch(void* const* d_in, const int* in_sizes, int n_in,
                              void* d_out, int out_size, void* d_ws, size_t ws_size,
                              hipStream_t stream) {
    const float* in   = (const float*)d_in[0];   // [3,1024,1024]
    const float* cw   = (const float*)d_in[1];   // [3,3,5,5]
    const float* cb   = (const float*)d_in[2];   // [3]
    const float* keys = (const float*)d_in[3];   // [100,3072]
    const float* vals = (const float*)d_in[4];   // [100,225]
    float* out = (float*)d_out;                  // [3,128,128] fp32

    unsigned* ctr = (unsigned*)d_ws;             // 2 barriers x 1KB (store-based)
    float* wsf = (float*)((char*)d_ws + 8192);   // plog1/plog2/wcomp scratch

    hipMemsetAsync(d_ws, 0, 2048, stream);       // zero barrier state
    k_fused<<<GRID, 512, 0, stream>>>(in, cw, cb, keys, vals, out, wsf, ctr);
}

// Round 13
// 100.993 us; speedup vs baseline: 1.2856x; 1.0130x over previous
//
#include <hip/hip_runtime.h>
#include <hip/hip_bf16.h>

// R25: == R22 EXACTLY (512 thr, 2 waves/SIMD, 2-barrier, plog[block][logit];
// dur 101.19 best) + two window-trims: G-TAP REGISTER PREFETCH AFTER BAR2
// and BARRIER SLEEP 8->1 ==
// R24 post-mortem: wcomp w_eff-fusion wash even coalesced (+1.1us) - the
// removed window came back as the wcomp MALL read window. REVERTED to pure
// R22 C'/w_eff. R23's lesson stands: coalescing = cross-lane per
// instruction (worth -28.7us).
// This round:
//  1. G-tap prefetch: G's taps (12 main + corrections) depend only on `in`
//     + entry geometry -> issue right after bar2, hold in registers across
//     F' (only syncthreads between, no asm clobbers -> no R14 spill
//     hazard; +~30 VGPR on 52 at 2 waves/SIMD = fine). G's last ~900cy
//     global window collapses to register reads. (R15's idea done right:
//     loads REPLACE G's own, issued ~5us earlier under F'.)
//  2. sleep(8)->sleep(1): at 1.4us/barrier the 512cy poll quantum is now
//     0.2-0.5us of detection quantization; old "sleep invariant" datum was
//     4-barrier-RMW-era through rocprof's inflated lens. R18 debunked the
//     poll-traffic concern.
// Pre-committed: dur 99.5-100.9 -> trims pay. >=100.9 flat -> structure at
// its latency floor (2 barriers + ~10 windows + entry); declare done.
// Ledger (measured): agent acquire/release fences forbidden (R4); cross-block
// data sc1 relaxed-agent only (R8); no dynamic-indexed register arrays (R7);
// no rolled global-load loops (R11); entry prefetch of static loads (R12);
// no long-lived regs across ASM-CLOBBER barriers (R14/R15; syncthreads-only
// spans are fine); dur_us ground truth, rocprof inflates poll loops ~5x,
// barrier ~1.4us (R16/R19); distributed barrier neutral (R18); warm-dup 22us
// (R19); redistribution -3.6 (R20); code size -1.5 (R21); 512thr TLP -4.9
// (R22); per-thread-contiguity layouts -28.7 (R23); wcomp fusion wash (R24).
// Deadlock safety: 128 blocks x 512 thr, launch_bounds(512,1), ~22KB LDS,
// VGPR ~90 -> co-resident on 256 CUs. Barrier state (2x1KB) zeroed.

#define GRID 128

#define LD1(p)     __hip_atomic_load((p), __ATOMIC_RELAXED, __HIP_MEMORY_SCOPE_AGENT)
#define ST1(p, v)  __hip_atomic_store((p), (v), __ATOMIC_RELAXED, __HIP_MEMORY_SCOPE_AGENT)

__device__ __forceinline__ float sigmoidf_(float z) {
    return 1.0f / (1.0f + expf(-z));
}

// base: 256 words (1KB). arrival[0..127]; release flag at word 160.
// No atomics anywhere: stores + loads only. (R12-validated, R17 form)
__device__ __forceinline__ void gbar(unsigned* base, int blk, int t) {
    asm volatile("s_waitcnt vmcnt(0)" ::: "memory");   // data sc1 stores visible
    __syncthreads();
    if (t == 0) ST1(base + blk, 1u);                   // arrival store, own word
    if (blk == 0) {
        if (t < 128) {                                 // 2 waves poll 128 words
            while (LD1(base + t) == 0u)
                __builtin_amdgcn_s_sleep(1);
        }
        __syncthreads();
        if (t == 0) ST1(base + 160, 1u);               // release flag, own line
    } else {
        if (t == 0) {
            while (LD1(base + 160) == 0u)
                __builtin_amdgcn_s_sleep(1);
        }
        __syncthreads();
    }
    asm volatile("" ::: "memory");
    __syncthreads();
}

// entry tap loads, ONE sample per wave (sample = blk*4 + wrow + rep*512).
__device__ __attribute__((noinline)) float2
key_prefetch(const float* __restrict__ in, int mul, int dbl, int blk,
             int lane, int wrow, int rep) {
    int s = blk * 4 + wrow + rep * 512;
    int ii = s >> 5, jj = s & 31;
    int qy = (ii * mul) >> 5, qx = (jj * mul) >> 5;
    int by = dbl ? 2 * qy : qy - 1;
    int bx = dbl ? 2 * qx : qx - 1;
    float xa, xb = 0.f;
    {
        int l = lane;                    // < 64 < 75: always a valid tap
        int ci = l / 25, rm = l % 25, r = rm / 5, cc = rm % 5;
        int y = by + r, x = bx + cc;
        xa = ((unsigned)y < 1024u && (unsigned)x < 1024u)
             ? 2.0f * in[ci * 1048576 + y * 1024 + x] - 1.0f : 0.f;
    }
    if (lane < 11) {
        int l = lane + 64;
        int ci = l / 25, rm = l % 25, r = rm / 5, cc = rm % 5;
        int y = by + r, x = bx + cc;
        xb = ((unsigned)y < 1024u && (unsigned)x < 1024u)
             ? 2.0f * in[ci * 1048576 + y * 1024 + x] - 1.0f : 0.f;
    }
    return make_float2(xa, xb);
}

// key value from taps -> skv LDS ([c*8 + rep*4 + wrow]); one sample per wave.
__device__ __attribute__((noinline)) void
key_stage(const float* __restrict__ sw, const float* __restrict__ sb,
          float xa, float xb, float* __restrict__ skv,
          int lane, int wrow, int rep) {
    float p0 = xa * sw[lane];
    float p1 = xa * sw[75 + lane];
    float p2 = xa * sw[150 + lane];
    if (lane < 11) {
        p0 += xb * sw[64 + lane];
        p1 += xb * sw[139 + lane];
        p2 += xb * sw[214 + lane];
    }
#pragma unroll
    for (int off = 32; off > 0; off >>= 1) {
        p0 += __shfl_xor(p0, off, 64);
        p1 += __shfl_xor(p1, off, 64);
        p2 += __shfl_xor(p2, off, 64);
    }
    if (lane == 0) {
        skv[0 * 8 + rep * 4 + wrow] = sigmoidf_(p0 + sb[0]);
        skv[1 * 8 + rep * 4 + wrow] = sigmoidf_(p1 + sb[1]);
        skv[2 * 8 + rep * 4 + wrow] = sigmoidf_(p2 + sb[2]);
    }
}

// logit partial (skc x skv) -> plog[block][logit] (lane-coalesced both sides).
__device__ __attribute__((noinline)) void
logit_partial(const float* __restrict__ skc, const float* __restrict__ skv,
              float* __restrict__ plog, int blk, int t) {
    if (t < 100) {
        float s = 0.f;
        const float* kc = skc + t * 25;
#pragma unroll
        for (int i = 0; i < 24; ++i) s += kc[i] * skv[i];
        ST1(plog + blk * 128 + t, s);
    }
}

// 4-group split reduce of plog[block][logit] -> pr[4][104]; per-instruction
// lane-coalesced (lanes tq read consecutive words); 32 loads/thread.
__device__ __attribute__((noinline)) void
reduce_split(const float* __restrict__ plog, float* __restrict__ pr, int t) {
    int g = t >> 7, tq = t & 127;
    if (tq < 100) {
        const float* p = plog + tq + g * 32 * 128;
        float s0 = 0.f, s1 = 0.f, s2 = 0.f, s3 = 0.f;
#pragma unroll
        for (int b = 0; b < 8; ++b) {
            s0 += LD1(p + (4 * b + 0) * 128);
            s1 += LD1(p + (4 * b + 1) * 128);
            s2 += LD1(p + (4 * b + 2) * 128);
            s3 += LD1(p + (4 * b + 3) * 128);
        }
        pr[g * 104 + tq] = (s0 + s1) + (s2 + s3);
    }
}

// softmax over sum of 4 partials, i<100 -> satt; one copy (has syncthreads).
__device__ __attribute__((noinline)) void
softmax_lds(const float* __restrict__ pr, float* __restrict__ satt,
            int lane, int wv) {
    if (wv == 0) {
        float v1 = (pr[lane] + pr[104 + lane]) + (pr[208 + lane] + pr[312 + lane]);
        float v2 = -3.4e38f;
        if (lane + 64 < 100) {
            int q = lane + 64;
            v2 = (pr[q] + pr[104 + q]) + (pr[208 + q] + pr[312 + q]);
        }
        float mx = fmaxf(v1, v2);
#pragma unroll
        for (int off = 32; off > 0; off >>= 1) mx = fmaxf(mx, __shfl_xor(mx, off, 64));
        float e1 = expf(v1 - mx);
        float e2 = (lane + 64 < 100) ? expf(v2 - mx) : 0.f;
        float s = e1 + e2;
#pragma unroll
        for (int off = 32; off > 0; off >>= 1) s += __shfl_xor(s, off, 64);
        float inv = 1.0f / s;
        satt[lane] = e1 * inv;
        if (lane + 64 < 100) satt[lane + 64] = e2 * inv;
    }
    __syncthreads();
}

// kern matvec: dst[t] = sum_n vals[n][t]*satt[n], dual accumulators; one copy.
__device__ __attribute__((noinline)) void
kern_phase(const float* __restrict__ vals, const float* __restrict__ satt,
           float* __restrict__ dst, int t) {
    if (t < 225) {
        float sa = 0.f, sb2 = 0.f;
#pragma unroll
        for (int n = 0; n < 50; ++n) {
            sa  += vals[(2 * n) * 225 + t] * satt[2 * n];
            sb2 += vals[(2 * n + 1) * 225 + t] * satt[2 * n + 1];
        }
        dst[t] = sa + sb2;
    }
}

__global__ __launch_bounds__(512, 1) void k_fused(
    const float* __restrict__ in, const float* __restrict__ cw,
    const float* __restrict__ cb, const float* __restrict__ keys,
    const float* __restrict__ vals, float* __restrict__ out,
    float* __restrict__ ws, unsigned* __restrict__ ctr)
{
    __shared__ float smem[5536];
    float* sk1  = smem;          // 225  kern1 (persists to tables)
    float* sk2  = smem + 232;    // 225  kern2
    float* satt = smem + 464;    // 100  softmax
    float* sw   = smem + 568;    // 225  conv weights, then w_eff
    float* sb   = smem + 800;    // 3    bias
    float* skv  = smem + 808;    // 24   block's key samples
    float* pr   = smem + 832;    // 416  reduce partials [4][104]
    float* skc  = smem + 1248;   // 2500 keys cols [t*25 + c*8+r*4+w]
    float* sWk  = smem + 3748;   // 468  W subset [(ci*3+o)*nk13 + k*13 + f]
    float* sWxk = smem + 4216;   // 36   Wx subset [(ci*3+o)*nk + k]
    float* sWy  = smem + 4252;   // 117  (blk 0 only)
    float* sWxy = smem + 4372;   // 9    (blk 0 only)
    float* sga  = smem + 4384;   // 1152 G combine [(h-1)*384 + ch*128 + j]

    float* plog1 = ws;           // [128 blocks][128 stride], 100 used (R22)
    float* plog2 = ws + 16384;

    const int t = threadIdx.x, lane = t & 63, wv = t >> 6;
    const int wrow = wv & 3, rep = wv >> 2;
    const int blk = blockIdx.x;

    // ---- entry prefetch: one sample per wave (s2v = 2 regs across bar1) ----
    float2 s1v = key_prefetch(in, 510, 1, blk, lane, wrow, rep);
    float2 s2v = key_prefetch(in, 1022, 0, blk, lane, wrow, rep);

    // ---- entry: keys columns for this block's 8 samples -> LDS (R14 fix) ----
    if (t < 100) {
        const float* kr = keys + t * 3072 + blk * 4;
#pragma unroll
        for (int c = 0; c < 3; ++c)
#pragma unroll
            for (int r = 0; r < 2; ++r) {
                float4 kk = *reinterpret_cast<const float4*>(kr + c * 1024 + r * 512);
                int o = t * 25 + c * 8 + r * 4;
                skc[o]     = kk.x;
                skc[o + 1] = kk.y;
                skc[o + 2] = kk.z;
                skc[o + 3] = kk.w;
            }
    }

    // ---- G geometry (j = output col, h = l-slot 0..3) ----
    const int j = t & 127, h = t >> 7;
    const int R = (blk * 4093) >> 7;
    const int C = (j * 4093) >> 7;
    const int ybase = (R + 6) >> 2, r0 = (R + 6) & 3, nk = (r0 == 0) ? 4 : 3;
    const int xbase = (C + 6) >> 2, f0 = (C + 6) & 3, nl = (f0 == 0) ? 4 : 3;
    const int nk13 = nk * 13;

    if (t < 225) sw[t] = cw[t];
    if (t < 3)   sb[t] = cb[t];
    __syncthreads();

    // ---- A: key1 samples -> skv, partial logits -> plog1 (all blocks) ----
    key_stage(sw, sb, s1v.x, s1v.y, skv, lane, wrow, rep);
    __syncthreads();
    logit_partial(skc, skv, plog1, blk, t);
    gbar(ctr, blk, t);

    // ---- C' (replicated): reduce -> softmax -> kern1 -> w_eff ----
    reduce_split(plog1, pr, t);
    __syncthreads();
    softmax_lds(pr, satt, lane, wv);
    kern_phase(vals, satt, sk1, t);
    __syncthreads();
    if (t < 225) {   // w_eff[co][ci][a][bb] = conv(convT(.,kern1)) composite
        int co = t / 75, rem = t % 75, ci = rem / 25, a = (rem % 25) / 5, bb = rem % 5;
        float s = 0.f;
#pragma unroll
        for (int c = 0; c < 5; ++c) {
            int u = c + 2 * a - 4;
            if ((unsigned)u >= 5u) continue;
#pragma unroll
            for (int d = 0; d < 5; ++d) {
                int v = d + 2 * bb - 4;
                if ((unsigned)v >= 5u) continue;
#pragma unroll
                for (int cm = 0; cm < 3; ++cm)
                    s += sk1[ci * 75 + cm * 25 + c * 5 + d] * cw[co * 75 + cm * 25 + u * 5 + v];
            }
        }
        sw[t] = s;    // nobody reads old sw in this phase
    }
    __syncthreads();

    // ---- D: key2 samples via w_eff -> skv, partials -> plog2 ----
    key_stage(sw, sb, s2v.x, s2v.y, skv, lane, wrow, rep);
    __syncthreads();
    logit_partial(skc, skv, plog2, blk, t);
    gbar(ctr + 256, blk, t);

    // ---- G-tap REGISTER PREFETCH (issued under F'; only syncthreads ahead,
    //      no asm clobbers -> registers live safely to G; R14 N/A) ----
    float gx0[4], gx1[4], gx2[4];
    float gy0 = 0.f, gy1 = 0.f, gy2 = 0.f;        // R==0 row correction taps
    float gz0[4], gz1[4], gz2[4];                 // C==0 col correction taps
    float gc0 = 0.f, gc1 = 0.f, gc2 = 0.f;        // corner taps
    {
        const int l = h;
        int ix = xbase - l;
        bool okx = (l < nl) && ((unsigned)ix < 1024u);
#pragma unroll
        for (int k = 0; k < 4; ++k) {
            int iy = ybase - k;
            bool ok = okx && (k < nk) && ((unsigned)iy < 1024u);
            int off = iy * 1024 + ix;
            gx0[k] = ok ? 2.0f * in[off] - 1.0f : 0.f;
            gx1[k] = ok ? 2.0f * in[1048576 + off] - 1.0f : 0.f;
            gx2[k] = ok ? 2.0f * in[2097152 + off] - 1.0f : 0.f;
        }
        if (R == 0 && okx) {
            gy0 = 2.0f * in[ix] - 1.0f;
            gy1 = 2.0f * in[1048576 + ix] - 1.0f;
            gy2 = 2.0f * in[2097152 + ix] - 1.0f;
        }
#pragma unroll
        for (int k = 0; k < 4; ++k) {
            int iy = ybase - k;
            bool ok = (C == 0) && (h == 0) && (k < nk) && ((unsigned)iy < 1024u);
            int off = iy * 1024;
            gz0[k] = ok ? 2.0f * in[off] - 1.0f : 0.f;
            gz1[k] = ok ? 2.0f * in[1048576 + off] - 1.0f : 0.f;
            gz2[k] = ok ? 2.0f * in[2097152 + off] - 1.0f : 0.f;
        }
        if (R == 0 && C == 0 && h == 0) {
            gc0 = 2.0f * in[0] - 1.0f;
            gc1 = 2.0f * in[1048576] - 1.0f;
            gc2 = 2.0f * in[2097152] - 1.0f;
        }
    }

    // ---- F' (replicated): reduce -> softmax -> kern2 -> tables ----
    reduce_split(plog2, pr, t);
    __syncthreads();
    softmax_lds(pr, satt, lane, wv);
    kern_phase(vals, satt, sk2, t);
    __syncthreads();
    // W subset: only rows e = r0 + 4k (k < nk) that THIS block's G uses.
    for (int idx = t; idx < 9 * nk13; idx += 512) {
        int cio = idx / nk13, rem = idx % nk13;
        int k = rem / 13, f = rem % 13;
        int e = r0 + 4 * k;
        int ci = cio / 3, o = cio % 3;
        float s = 0.f;
#pragma unroll
        for (int c = 0; c < 5; ++c) {
            int a = e - 2 * c;
            if ((unsigned)a >= 5u) continue;
#pragma unroll
            for (int d = 0; d < 5; ++d) {
                int b2 = f - 2 * d;
                if ((unsigned)b2 >= 5u) continue;
#pragma unroll
                for (int cm = 0; cm < 3; ++cm)
                    s += sk1[ci * 75 + cm * 25 + c * 5 + d] * sk2[cm * 75 + o * 25 + a * 5 + b2];
            }
        }
        sWk[idx] = s;
    }
    if (t >= 472 && t < 472 + 9 * nk) {   // Wx subset (phantom col), idle threads
        int q = t - 472;
        int cio = q / nk, k = q % nk;
        int e = r0 + 4 * k;
        int ci = cio / 3, o = cio % 3;
        float s = 0.f;
#pragma unroll
        for (int c = 0; c < 5; ++c) {
            int a = e - 2 * c;
            if ((unsigned)a >= 5u) continue;
#pragma unroll
            for (int cm = 0; cm < 3; ++cm)
                s += sk1[ci * 75 + cm * 25 + c * 5 + 1] * sk2[cm * 75 + o * 25 + a * 5 + 4];
        }
        sWxk[cio * nk + k] = s;
    }
    if (blk == 0) {   // R==0 only for block 0: Wy full f-range + Wxy
        if (t >= 256 && t < 256 + 117) {
            int q = t - 256;
            int ci = q / 39, o = (q % 39) / 13, f = q % 13;
            float s = 0.f;
#pragma unroll
            for (int d = 0; d < 5; ++d) {
                int b2 = f - 2 * d;
                if ((unsigned)b2 >= 5u) continue;
#pragma unroll
                for (int cm = 0; cm < 3; ++cm)
                    s += sk1[ci * 75 + cm * 25 + 5 + d] * sk2[cm * 75 + o * 25 + 20 + b2];
            }
            sWy[(ci * 3 + o) * 13 + f] = s;
        }
        if (t >= 384 && t < 393) {
            int q = t - 384;
            int ci = q / 3, o = q % 3;
            float s = 0.f;
#pragma unroll
            for (int cm = 0; cm < 3; ++cm)
                s += sk1[ci * 75 + cm * 25 + 5 + 1] * sk2[cm * 75 + o * 25 + 20 + 4];
            sWxy[ci * 3 + o] = s;
        }
    }
    __syncthreads();

    // ---- G: 4-way split (h = l-slot), taps from PREFETCHED registers ----
    {
        float a0 = 0.f, a1 = 0.f, a2 = 0.f;
        const int l = h;
        if (l < nl) {
            int ix = xbase - l;
            if ((unsigned)ix < 1024u) {
                int f = f0 + 4 * l;
#pragma unroll
                for (int k = 0; k < 4; ++k) {
                    if (k < nk) {
                        int wi = k * 13 + f;
                        a0 += gx0[k] * sWk[wi]            + gx1[k] * sWk[3 * nk13 + wi] + gx2[k] * sWk[6 * nk13 + wi];
                        a1 += gx0[k] * sWk[nk13 + wi]     + gx1[k] * sWk[4 * nk13 + wi] + gx2[k] * sWk[7 * nk13 + wi];
                        a2 += gx0[k] * sWk[2 * nk13 + wi] + gx1[k] * sWk[5 * nk13 + wi] + gx2[k] * sWk[8 * nk13 + wi];
                    }
                }
                if (R == 0) {   // block 0: phantom-row correction (prefetched)
                    a0 -= gy0 * sWy[f]      + gy1 * sWy[39 + f] + gy2 * sWy[78 + f];
                    a1 -= gy0 * sWy[13 + f] + gy1 * sWy[52 + f] + gy2 * sWy[91 + f];
                    a2 -= gy0 * sWy[26 + f] + gy1 * sWy[65 + f] + gy2 * sWy[104 + f];
                }
            }
        }
        if (C == 0 && h == 0) {   // j==0: phantom-col correction (prefetched)
#pragma unroll
            for (int k = 0; k < 4; ++k) {
                if (k < nk) {
                    a0 -= gz0[k] * sWxk[k]          + gz1[k] * sWxk[3 * nk + k] + gz2[k] * sWxk[6 * nk + k];
                    a1 -= gz0[k] * sWxk[nk + k]     + gz1[k] * sWxk[4 * nk + k] + gz2[k] * sWxk[7 * nk + k];
                    a2 -= gz0[k] * sWxk[2 * nk + k] + gz1[k] * sWxk[5 * nk + k] + gz2[k] * sWxk[8 * nk + k];
                }
            }
        }
        if (R == 0 && C == 0 && h == 0) {
            a0 += gc0 * sWxy[0] + gc1 * sWxy[3] + gc2 * sWxy[6];
            a1 += gc0 * sWxy[1] + gc1 * sWxy[4] + gc2 * sWxy[7];
            a2 += gc0 * sWxy[2] + gc1 * sWxy[5] + gc2 * sWxy[8];
        }
        if (h > 0) {
            int base = (h - 1) * 384;
            sga[base + j] = a0; sga[base + 128 + j] = a1; sga[base + 256 + j] = a2;
        }
        __syncthreads();
        if (h == 0) {
            int T = blk * 128 + j;
            float b0 = a0 + sga[j]       + sga[384 + j]       + sga[768 + j];
            float b1 = a1 + sga[128 + j] + sga[384 + 128 + j] + sga[768 + 128 + j];
            float b2 = a2 + sga[256 + j] + sga[384 + 256 + j] + sga[768 + 256 + j];
            out[T]             = sigmoidf_(b0);
            out[16384 + T]     = sigmoidf_(b1);
            out[2 * 16384 + T] = sigmoidf_(b2);
        }
    }
}

extern "C" void kernel_launch(void* const* d_in, const int* in_sizes, int n_in,
                              void* d_out, int out_size, void* d_ws, size_t ws_size,
                              hipStream_t stream) {
    const float* in   = (const float*)d_in[0];   // [3,1024,1024]
    const float* cw   = (const float*)d_in[1];   // [3,3,5,5]
    const float* cb   = (const float*)d_in[2];   // [3]
    const float* keys = (const float*)d_in[3];   // [100,3072]
    const float* vals = (const float*)d_in[4];   // [100,225]
    float* out = (float*)d_out;                  // [3,128,128] fp32

    unsigned* ctr = (unsigned*)d_ws;             // 2 barriers x 1KB (store-based)
    float* wsf = (float*)((char*)d_ws + 8192);   // plog1/plog2 scratch

    hipMemsetAsync(d_ws, 0, 2048, stream);       // zero barrier state
    k_fused<<<GRID, 512, 0, stream>>>(in, cw, cb, keys, vals, out, wsf, ctr);
}